// Round 3
// baseline (142.756 us; speedup 1.0000x reference)
//
#include <hip/hip_runtime.h>
#include <hip/hip_bf16.h>
#include <math.h>

#define D_DIM 192
#define H_DIM 224
#define W_DIM 192
#define ROWS_PER_BLOCK 4
#define NUM_XCD 8

// ---------------------------------------------------------------------------
// Kernel 1: compose the 4x4 transform on-device (single thread).
// T = inv(flo_v2r) @ (Tci @ Ttr @ Trot @ Tsc @ Tc) @ ref_v2r
// Writes rows 0..2 (12 floats) of T to Tout.
// ---------------------------------------------------------------------------

__device__ inline void mm4(const float* A, const float* B, float* C) {
    for (int r = 0; r < 4; ++r)
        for (int c = 0; c < 4; ++c) {
            float s = 0.f;
            for (int t = 0; t < 4; ++t) s += A[r * 4 + t] * B[t * 4 + c];
            C[r * 4 + c] = s;
        }
}

__device__ inline void inv4(const float* Ain, float* out) {
    float a[4][8];
    for (int r = 0; r < 4; ++r) {
        for (int c = 0; c < 4; ++c) a[r][c] = Ain[r * 4 + c];
        for (int c = 0; c < 4; ++c) a[r][4 + c] = (r == c) ? 1.f : 0.f;
    }
    for (int col = 0; col < 4; ++col) {
        int piv = col;
        float best = fabsf(a[col][col]);
        for (int r = col + 1; r < 4; ++r) {
            float v = fabsf(a[r][col]);
            if (v > best) { best = v; piv = r; }
        }
        if (piv != col) {
            for (int c = 0; c < 8; ++c) {
                float t = a[col][c]; a[col][c] = a[piv][c]; a[piv][c] = t;
            }
        }
        float inv = 1.f / a[col][col];
        for (int c = 0; c < 8; ++c) a[col][c] *= inv;
        for (int r = 0; r < 4; ++r) {
            if (r == col) continue;
            float f = a[r][col];
            for (int c = 0; c < 8; ++c) a[r][c] -= f * a[col][c];
        }
    }
    for (int r = 0; r < 4; ++r)
        for (int c = 0; c < 4; ++c) out[r * 4 + c] = a[r][4 + c];
}

__global__ void compute_T_kernel(const float* __restrict__ ang,
                                 const float* __restrict__ tr,
                                 const float* __restrict__ scl,
                                 const float* __restrict__ ref_v2r,
                                 const float* __restrict__ flo_v2r,
                                 float* __restrict__ Tout) {
    if (threadIdx.x != 0 || blockIdx.x != 0) return;

    const float cogx = 96.f, cogy = 112.f, cogz = 96.f;

    float cx = cosf(ang[0]), sx = sinf(ang[0]);
    float cy = cosf(ang[1]), sy = sinf(ang[1]);
    float cz = cosf(ang[2]), sz = sinf(ang[2]);

    float Rx[9] = {1, 0, 0, 0, cx, -sx, 0, sx, cx};
    float Ry[9] = {cy, 0, sy, 0, 1, 0, -sy, 0, cy};
    float Rz[9] = {cz, -sz, 0, sz, cz, 0, 0, 0, 1};
    float Ryz[9], R[9];
    for (int r = 0; r < 3; ++r)
        for (int c = 0; c < 3; ++c) {
            float s = 0.f;
            for (int t = 0; t < 3; ++t) s += Ry[r * 3 + t] * Rz[t * 3 + c];
            Ryz[r * 3 + c] = s;
        }
    for (int r = 0; r < 3; ++r)
        for (int c = 0; c < 3; ++c) {
            float s = 0.f;
            for (int t = 0; t < 3; ++t) s += Rx[r * 3 + t] * Ryz[t * 3 + c];
            R[r * 3 + c] = s;
        }

    float s0 = expf(scl[0]), s1 = expf(scl[1]), s2 = expf(scl[2]);

    float Tc[16]   = {1,0,0,-cogx, 0,1,0,-cogy, 0,0,1,-cogz, 0,0,0,1};
    float Tci[16]  = {1,0,0, cogx, 0,1,0, cogy, 0,0,1, cogz, 0,0,0,1};
    float Tsc[16]  = {s0,0,0,0, 0,s1,0,0, 0,0,s2,0, 0,0,0,1};
    float Ttr[16]  = {1,0,0,tr[0], 0,1,0,tr[1], 0,0,1,tr[2], 0,0,0,1};
    float Trot[16] = {R[0],R[1],R[2],0, R[3],R[4],R[5],0, R[6],R[7],R[8],0, 0,0,0,1};

    float m1[16], m2[16], m3[16], Trig[16];
    mm4(Tci, Ttr, m1);
    mm4(m1, Trot, m2);
    mm4(m2, Tsc, m3);
    mm4(m3, Tc, Trig);

    float floinv[16], m4[16], T[16];
    inv4(flo_v2r, floinv);
    mm4(floinv, Trig, m4);
    mm4(m4, ref_v2r, T);

    for (int q = 0; q < 12; ++q) Tout[q] = T[q];
}

// ---------------------------------------------------------------------------
// Kernel 2: trilinear resample.
// - 1D grid, XCD-slab swizzle (blockIdx.x % 8 -> contiguous slab per XCD).
// - 4 rows (same i, consecutive j) per block: 32 gathers in flight per thread.
// - Nontemporal stores for the output.
// NUMERICS: coordinate expression must stay EXACTLY as round 1
// (t00*fi + t01*fj + t02*fk + t03, left-to-right) — manual reassociation
// flips the ok-mask at the boundary and fails validation (round 2 lesson).
// ---------------------------------------------------------------------------

__global__ __launch_bounds__(W_DIM) void resample_kernel(
    const float* __restrict__ vol,
    const float* __restrict__ T,
    float* __restrict__ out) {

    constexpr int NBLK = (D_DIM * H_DIM) / ROWS_PER_BLOCK;  // 10752
    constexpr int PER_XCD = NBLK / NUM_XCD;                 // 1344

    const int b = blockIdx.x;
    const int xcd = b & (NUM_XCD - 1);
    const int q = b >> 3;
    const int sb = xcd * PER_XCD + q;        // slab-contiguous block index
    const int row_base = sb * ROWS_PER_BLOCK;
    const int i = row_base / H_DIM;          // 224 % 4 == 0 -> all 4 rows same i
    const int jbase = row_base % H_DIM;
    const int k = threadIdx.x;

    const float t00 = T[0],  t01 = T[1],  t02 = T[2],  t03 = T[3];
    const float t10 = T[4],  t11 = T[5],  t12 = T[6],  t13 = T[7];
    const float t20 = T[8],  t21 = T[9],  t22 = T[10], t23 = T[11];

    const float fi = (float)i, fk = (float)k;

    float c[ROWS_PER_BLOCK][8];
    float wi[ROWS_PER_BLOCK], wj[ROWS_PER_BLOCK], wk[ROWS_PER_BLOCK];
    bool okr[ROWS_PER_BLOCK];

    // Phase 1: addresses + all 32 gather loads in flight
#pragma unroll
    for (int r = 0; r < ROWS_PER_BLOCK; ++r) {
        const float fj = (float)(jbase + r);
        // EXACT round-1 expression order — do not reassociate (ok-mask edge).
        const float di = t00 * fi + t01 * fj + t02 * fk + t03;
        const float dj = t10 * fi + t11 * fj + t12 * fk + t13;
        const float dk = t20 * fi + t21 * fj + t22 * fk + t23;

        okr[r] = (di > 0.f) & (dj > 0.f) & (dk > 0.f) &
                 (di <= (float)(D_DIM - 1)) &
                 (dj <= (float)(H_DIM - 1)) &
                 (dk <= (float)(W_DIM - 1));

        float ffi = fminf(fmaxf(floorf(di), 0.f), (float)(D_DIM - 1));
        float ffj = fminf(fmaxf(floorf(dj), 0.f), (float)(H_DIM - 1));
        float ffk = fminf(fmaxf(floorf(dk), 0.f), (float)(W_DIM - 1));

        wi[r] = di - ffi; wj[r] = dj - ffj; wk[r] = dk - ffk;

        const int i0 = (int)ffi, j0 = (int)ffj, k0 = (int)ffk;
        const int i1 = min(i0 + 1, D_DIM - 1);
        const int j1 = min(j0 + 1, H_DIM - 1);
        const int k1 = min(k0 + 1, W_DIM - 1);

        const int base00 = (i0 * H_DIM + j0) * W_DIM;
        const int base01 = (i0 * H_DIM + j1) * W_DIM;
        const int base10 = (i1 * H_DIM + j0) * W_DIM;
        const int base11 = (i1 * H_DIM + j1) * W_DIM;

        c[r][0] = vol[base00 + k0];
        c[r][1] = vol[base10 + k0];
        c[r][2] = vol[base01 + k0];
        c[r][3] = vol[base11 + k0];
        c[r][4] = vol[base00 + k1];
        c[r][5] = vol[base10 + k1];
        c[r][6] = vol[base01 + k1];
        c[r][7] = vol[base11 + k1];
    }

    // Phase 2: interpolate + store
#pragma unroll
    for (int r = 0; r < ROWS_PER_BLOCK; ++r) {
        const float omwi = 1.f - wi[r], omwj = 1.f - wj[r], omwk = 1.f - wk[r];
        const float v = ((c[r][0] * omwi + c[r][1] * wi[r]) * omwj +
                         (c[r][2] * omwi + c[r][3] * wi[r]) * wj[r]) * omwk +
                        ((c[r][4] * omwi + c[r][5] * wi[r]) * omwj +
                         (c[r][6] * omwi + c[r][7] * wi[r]) * wj[r]) * wk[r];
        const float res = okr[r] ? v : 0.f;
        __builtin_nontemporal_store(res, &out[(i * H_DIM + (jbase + r)) * W_DIM + k]);
    }
}

// ---------------------------------------------------------------------------

extern "C" void kernel_launch(void* const* d_in, const int* in_sizes, int n_in,
                              void* d_out, int out_size, void* d_ws, size_t ws_size,
                              hipStream_t stream) {
    const float* image_targ  = (const float*)d_in[0];
    const float* angle       = (const float*)d_in[1];
    const float* translation = (const float*)d_in[2];
    const float* scaling     = (const float*)d_in[3];
    const float* ref_v2r     = (const float*)d_in[4];
    const float* flo_v2r     = (const float*)d_in[5];
    float* out = (float*)d_out;
    float* Tmat = (float*)d_ws;  // 12 floats

    compute_T_kernel<<<1, 1, 0, stream>>>(angle, translation, scaling,
                                          ref_v2r, flo_v2r, Tmat);

    const int nblk = (D_DIM * H_DIM) / ROWS_PER_BLOCK;  // 10752
    resample_kernel<<<nblk, W_DIM, 0, stream>>>(image_targ, Tmat, out);
}

// Round 4
// 114.937 us; speedup vs baseline: 1.2420x; 1.2420x over previous
//
#include <hip/hip_runtime.h>
#include <hip/hip_bf16.h>
#include <math.h>

#define D_DIM 192
#define H_DIM 224
#define W_DIM 192
#define TILE_ROWS 8              // j-rows per block (224 % 8 == 0 -> same i)
#define BLOCK 256
#define VPT 6                    // voxels per thread = 8*192/256
#define NUM_XCD 8

// ---------------------------------------------------------------------------
// Kernel 1: compose the 4x4 transform on-device (single thread).
// ---------------------------------------------------------------------------

__device__ inline void mm4(const float* A, const float* B, float* C) {
    for (int r = 0; r < 4; ++r)
        for (int c = 0; c < 4; ++c) {
            float s = 0.f;
            for (int t = 0; t < 4; ++t) s += A[r * 4 + t] * B[t * 4 + c];
            C[r * 4 + c] = s;
        }
}

__device__ inline void inv4(const float* Ain, float* out) {
    float a[4][8];
    for (int r = 0; r < 4; ++r) {
        for (int c = 0; c < 4; ++c) a[r][c] = Ain[r * 4 + c];
        for (int c = 0; c < 4; ++c) a[r][4 + c] = (r == c) ? 1.f : 0.f;
    }
    for (int col = 0; col < 4; ++col) {
        int piv = col;
        float best = fabsf(a[col][col]);
        for (int r = col + 1; r < 4; ++r) {
            float v = fabsf(a[r][col]);
            if (v > best) { best = v; piv = r; }
        }
        if (piv != col) {
            for (int c = 0; c < 8; ++c) {
                float t = a[col][c]; a[col][c] = a[piv][c]; a[piv][c] = t;
            }
        }
        float inv = 1.f / a[col][col];
        for (int c = 0; c < 8; ++c) a[col][c] *= inv;
        for (int r = 0; r < 4; ++r) {
            if (r == col) continue;
            float f = a[r][col];
            for (int c = 0; c < 8; ++c) a[r][c] -= f * a[col][c];
        }
    }
    for (int r = 0; r < 4; ++r)
        for (int c = 0; c < 4; ++c) out[r * 4 + c] = a[r][4 + c];
}

__global__ void compute_T_kernel(const float* __restrict__ ang,
                                 const float* __restrict__ tr,
                                 const float* __restrict__ scl,
                                 const float* __restrict__ ref_v2r,
                                 const float* __restrict__ flo_v2r,
                                 float* __restrict__ Tout) {
    if (threadIdx.x != 0 || blockIdx.x != 0) return;

    const float cogx = 96.f, cogy = 112.f, cogz = 96.f;

    float cx = cosf(ang[0]), sx = sinf(ang[0]);
    float cy = cosf(ang[1]), sy = sinf(ang[1]);
    float cz = cosf(ang[2]), sz = sinf(ang[2]);

    float Rx[9] = {1, 0, 0, 0, cx, -sx, 0, sx, cx};
    float Ry[9] = {cy, 0, sy, 0, 1, 0, -sy, 0, cy};
    float Rz[9] = {cz, -sz, 0, sz, cz, 0, 0, 0, 1};
    float Ryz[9], R[9];
    for (int r = 0; r < 3; ++r)
        for (int c = 0; c < 3; ++c) {
            float s = 0.f;
            for (int t = 0; t < 3; ++t) s += Ry[r * 3 + t] * Rz[t * 3 + c];
            Ryz[r * 3 + c] = s;
        }
    for (int r = 0; r < 3; ++r)
        for (int c = 0; c < 3; ++c) {
            float s = 0.f;
            for (int t = 0; t < 3; ++t) s += Rx[r * 3 + t] * Ryz[t * 3 + c];
            R[r * 3 + c] = s;
        }

    float s0 = expf(scl[0]), s1 = expf(scl[1]), s2 = expf(scl[2]);

    float Tc[16]   = {1,0,0,-cogx, 0,1,0,-cogy, 0,0,1,-cogz, 0,0,0,1};
    float Tci[16]  = {1,0,0, cogx, 0,1,0, cogy, 0,0,1, cogz, 0,0,0,1};
    float Tsc[16]  = {s0,0,0,0, 0,s1,0,0, 0,0,s2,0, 0,0,0,1};
    float Ttr[16]  = {1,0,0,tr[0], 0,1,0,tr[1], 0,0,1,tr[2], 0,0,0,1};
    float Trot[16] = {R[0],R[1],R[2],0, R[3],R[4],R[5],0, R[6],R[7],R[8],0, 0,0,0,1};

    float m1[16], m2[16], m3[16], Trig[16];
    mm4(Tci, Ttr, m1);
    mm4(m1, Trot, m2);
    mm4(m2, Tsc, m3);
    mm4(m3, Tc, Trig);

    float floinv[16], m4[16], T[16];
    inv4(flo_v2r, floinv);
    mm4(floinv, Trig, m4);
    mm4(m4, ref_v2r, T);

    for (int q = 0; q < 12; ++q) Tout[q] = T[q];
}

// ---------------------------------------------------------------------------
// Kernel 2: trilinear resample.
// - Tile = 8 consecutive j-rows (same i) x 192 k = 1536 voxels; 256 threads,
//   6 voxels/thread. Phase 1 issues ALL 24 float2 gathers before consuming.
// - float2 paired gathers: (k0, k0+1) are adjacent -> 4 loads/voxel instead
//   of 8. Border: koff = min(k0, W-2) keeps the 8B load in-bounds; select
//   .x/.y reproduces the reference's clamped-k1 semantics exactly.
// - XCD slab swizzle for L2 locality (proven: FETCH 92->18 MB in R3).
// - NUMERICS: di/dj/dk use the exact 4-term left-to-right expression
//   (round-2 lesson: reassociation flips the ok-mask at the boundary).
// - __launch_bounds__(256,4): allow 128 VGPRs so the 24 loads actually stay
//   in flight (R3 failed at VGPR=32 -> compiler serialized the gathers).
// ---------------------------------------------------------------------------

typedef float vf2 __attribute__((ext_vector_type(2)));

__global__ __launch_bounds__(BLOCK, 4) void resample_kernel(
    const float* __restrict__ vol,
    const float* __restrict__ T,
    float* __restrict__ out) {

    constexpr int TILES_PER_I = H_DIM / TILE_ROWS;            // 28
    constexpr int NBLK = D_DIM * TILES_PER_I;                 // 5376
    constexpr int PER_XCD = NBLK / NUM_XCD;                   // 672

    const int b = blockIdx.x;
    const int xcd = b & (NUM_XCD - 1);
    const int q = b >> 3;
    const int sb = xcd * PER_XCD + q;          // slab-contiguous tile index
    const int i = sb / TILES_PER_I;
    const int jbase = (sb - i * TILES_PER_I) * TILE_ROWS;
    const int tid = threadIdx.x;

    const float t00 = T[0],  t01 = T[1],  t02 = T[2],  t03 = T[3];
    const float t10 = T[4],  t11 = T[5],  t12 = T[6],  t13 = T[7];
    const float t20 = T[8],  t21 = T[9],  t22 = T[10], t23 = T[11];

    const float fi = (float)i;

    vf2  p00[VPT], p10[VPT], p01[VPT], p11[VPT];
    float wi[VPT], wj[VPT], wk[VPT];
    int   sel[VPT];
    bool  okr[VPT];

    // ---- Phase 1: all addresses + all 24 float2 gathers in flight ----
#pragma unroll
    for (int t = 0; t < VPT; ++t) {
        const int v = tid + t * BLOCK;         // 0..1535
        const int jo = v / W_DIM;              // 0..7
        const int k = v - jo * W_DIM;          // 0..191
        const float fj = (float)(jbase + jo);
        const float fk = (float)k;

        // EXACT reference expression order — do not reassociate (ok-mask edge).
        const float di = t00 * fi + t01 * fj + t02 * fk + t03;
        const float dj = t10 * fi + t11 * fj + t12 * fk + t13;
        const float dk = t20 * fi + t21 * fj + t22 * fk + t23;

        okr[t] = (di > 0.f) & (dj > 0.f) & (dk > 0.f) &
                 (di <= (float)(D_DIM - 1)) &
                 (dj <= (float)(H_DIM - 1)) &
                 (dk <= (float)(W_DIM - 1));

        float ffi = fminf(fmaxf(floorf(di), 0.f), (float)(D_DIM - 1));
        float ffj = fminf(fmaxf(floorf(dj), 0.f), (float)(H_DIM - 1));
        float ffk = fminf(fmaxf(floorf(dk), 0.f), (float)(W_DIM - 1));

        wi[t] = di - ffi; wj[t] = dj - ffj; wk[t] = dk - ffk;

        const int i0 = (int)ffi, j0 = (int)ffj, k0 = (int)ffk;
        const int i1 = min(i0 + 1, D_DIM - 1);
        const int j1 = min(j0 + 1, H_DIM - 1);
        const int koff = min(k0, W_DIM - 2);   // 8B load stays in-bounds
        sel[t] = k0 - koff;                    // 1 iff k0 == W-1

        const int base00 = (i0 * H_DIM + j0) * W_DIM + koff;
        const int base01 = (i0 * H_DIM + j1) * W_DIM + koff;
        const int base10 = (i1 * H_DIM + j0) * W_DIM + koff;
        const int base11 = (i1 * H_DIM + j1) * W_DIM + koff;

        p00[t] = *(const vf2*)(vol + base00);
        p10[t] = *(const vf2*)(vol + base10);
        p01[t] = *(const vf2*)(vol + base01);
        p11[t] = *(const vf2*)(vol + base11);
    }

    // ---- Phase 2: interpolate + coalesced nontemporal store ----
    const int out_base = (i * H_DIM + jbase) * W_DIM;
#pragma unroll
    for (int t = 0; t < VPT; ++t) {
        // c000 = vol[k0]: .x normally, .y when k0 == W-1 (koff = k0-1).
        // c001 = vol[min(k0+1, W-1)] = .y always.
        const float c000 = sel[t] ? p00[t].y : p00[t].x;
        const float c100 = sel[t] ? p10[t].y : p10[t].x;
        const float c010 = sel[t] ? p01[t].y : p01[t].x;
        const float c110 = sel[t] ? p11[t].y : p11[t].x;
        const float c001 = p00[t].y;
        const float c101 = p10[t].y;
        const float c011 = p01[t].y;
        const float c111 = p11[t].y;

        const float omwi = 1.f - wi[t], omwj = 1.f - wj[t], omwk = 1.f - wk[t];
        const float val = ((c000 * omwi + c100 * wi[t]) * omwj +
                           (c010 * omwi + c110 * wi[t]) * wj[t]) * omwk +
                          ((c001 * omwi + c101 * wi[t]) * omwj +
                           (c011 * omwi + c111 * wi[t]) * wj[t]) * wk[t];
        const float res = okr[t] ? val : 0.f;
        __builtin_nontemporal_store(res, &out[out_base + tid + t * BLOCK]);
    }
}

// ---------------------------------------------------------------------------

extern "C" void kernel_launch(void* const* d_in, const int* in_sizes, int n_in,
                              void* d_out, int out_size, void* d_ws, size_t ws_size,
                              hipStream_t stream) {
    const float* image_targ  = (const float*)d_in[0];
    const float* angle       = (const float*)d_in[1];
    const float* translation = (const float*)d_in[2];
    const float* scaling     = (const float*)d_in[3];
    const float* ref_v2r     = (const float*)d_in[4];
    const float* flo_v2r     = (const float*)d_in[5];
    float* out = (float*)d_out;
    float* Tmat = (float*)d_ws;  // 12 floats

    compute_T_kernel<<<1, 1, 0, stream>>>(angle, translation, scaling,
                                          ref_v2r, flo_v2r, Tmat);

    const int nblk = D_DIM * (H_DIM / TILE_ROWS);  // 5376
    resample_kernel<<<nblk, BLOCK, 0, stream>>>(image_targ, Tmat, out);
}

// Round 5
// 114.346 us; speedup vs baseline: 1.2485x; 1.0052x over previous
//
#include <hip/hip_runtime.h>
#include <hip/hip_bf16.h>
#include <math.h>

#define D_DIM 192
#define H_DIM 224
#define W_DIM 192
#define TILE_ROWS 4              // j-rows per block (224 % 4 == 0 -> same i)
#define BLOCK 192                // one thread per k -> no div/mod in hot path
#define NUM_XCD 8

// ---------------------------------------------------------------------------
// Kernel 1: compose the 4x4 transform on-device (single thread).
// ---------------------------------------------------------------------------

__device__ inline void mm4(const float* A, const float* B, float* C) {
    for (int r = 0; r < 4; ++r)
        for (int c = 0; c < 4; ++c) {
            float s = 0.f;
            for (int t = 0; t < 4; ++t) s += A[r * 4 + t] * B[t * 4 + c];
            C[r * 4 + c] = s;
        }
}

__device__ inline void inv4(const float* Ain, float* out) {
    float a[4][8];
    for (int r = 0; r < 4; ++r) {
        for (int c = 0; c < 4; ++c) a[r][c] = Ain[r * 4 + c];
        for (int c = 0; c < 4; ++c) a[r][4 + c] = (r == c) ? 1.f : 0.f;
    }
    for (int col = 0; col < 4; ++col) {
        int piv = col;
        float best = fabsf(a[col][col]);
        for (int r = col + 1; r < 4; ++r) {
            float v = fabsf(a[r][col]);
            if (v > best) { best = v; piv = r; }
        }
        if (piv != col) {
            for (int c = 0; c < 8; ++c) {
                float t = a[col][c]; a[col][c] = a[piv][c]; a[piv][c] = t;
            }
        }
        float inv = 1.f / a[col][col];
        for (int c = 0; c < 8; ++c) a[col][c] *= inv;
        for (int r = 0; r < 4; ++r) {
            if (r == col) continue;
            float f = a[r][col];
            for (int c = 0; c < 8; ++c) a[r][c] -= f * a[col][c];
        }
    }
    for (int r = 0; r < 4; ++r)
        for (int c = 0; c < 4; ++c) out[r * 4 + c] = a[r][4 + c];
}

__global__ void compute_T_kernel(const float* __restrict__ ang,
                                 const float* __restrict__ tr,
                                 const float* __restrict__ scl,
                                 const float* __restrict__ ref_v2r,
                                 const float* __restrict__ flo_v2r,
                                 float* __restrict__ Tout) {
    if (threadIdx.x != 0 || blockIdx.x != 0) return;

    const float cogx = 96.f, cogy = 112.f, cogz = 96.f;

    float cx = cosf(ang[0]), sx = sinf(ang[0]);
    float cy = cosf(ang[1]), sy = sinf(ang[1]);
    float cz = cosf(ang[2]), sz = sinf(ang[2]);

    float Rx[9] = {1, 0, 0, 0, cx, -sx, 0, sx, cx};
    float Ry[9] = {cy, 0, sy, 0, 1, 0, -sy, 0, cy};
    float Rz[9] = {cz, -sz, 0, sz, cz, 0, 0, 0, 1};
    float Ryz[9], R[9];
    for (int r = 0; r < 3; ++r)
        for (int c = 0; c < 3; ++c) {
            float s = 0.f;
            for (int t = 0; t < 3; ++t) s += Ry[r * 3 + t] * Rz[t * 3 + c];
            Ryz[r * 3 + c] = s;
        }
    for (int r = 0; r < 3; ++r)
        for (int c = 0; c < 3; ++c) {
            float s = 0.f;
            for (int t = 0; t < 3; ++t) s += Rx[r * 3 + t] * Ryz[t * 3 + c];
            R[r * 3 + c] = s;
        }

    float s0 = expf(scl[0]), s1 = expf(scl[1]), s2 = expf(scl[2]);

    float Tc[16]   = {1,0,0,-cogx, 0,1,0,-cogy, 0,0,1,-cogz, 0,0,0,1};
    float Tci[16]  = {1,0,0, cogx, 0,1,0, cogy, 0,0,1, cogz, 0,0,0,1};
    float Tsc[16]  = {s0,0,0,0, 0,s1,0,0, 0,0,s2,0, 0,0,0,1};
    float Ttr[16]  = {1,0,0,tr[0], 0,1,0,tr[1], 0,0,1,tr[2], 0,0,0,1};
    float Trot[16] = {R[0],R[1],R[2],0, R[3],R[4],R[5],0, R[6],R[7],R[8],0, 0,0,0,1};

    float m1[16], m2[16], m3[16], Trig[16];
    mm4(Tci, Ttr, m1);
    mm4(m1, Trot, m2);
    mm4(m2, Tsc, m3);
    mm4(m3, Tc, Trig);

    float floinv[16], m4[16], T[16];
    inv4(flo_v2r, floinv);
    mm4(floinv, Trig, m4);
    mm4(m4, ref_v2r, T);

    for (int q = 0; q < 12; ++q) Tout[q] = T[q];
}

// ---------------------------------------------------------------------------
// Kernel 2: trilinear resample.
// - Tile = 4 consecutive j-rows (same i) x 192 k. block=192 -> k = tid (no
//   div/mod), 4 voxels/thread, 16 float2 gathers per thread.
// - __syncthreads() between load phase and consume phase: emits
//   s_waitcnt vmcnt(0) + s_barrier and (memory-ordering semantics) prevents
//   the compiler from sinking loads into the consume phase. This forces all
//   16 results live across the barrier -> real MLP. (R3/R4 lesson: a cap via
//   __launch_bounds__ does NOT stop the compiler from interleaving at
//   VGPR=32..36 and serializing the gathers.)
// - float2 paired gathers (k0,k0+1): 4 loads/voxel. koff=min(k0,W-2) keeps
//   the 8B load in-bounds; .x/.y select reproduces clamped-k1 semantics.
// - XCD slab swizzle (proven in R3: FETCH 92 -> 18 MB).
// - NUMERICS: di/dj/dk exactly as R1 (left-to-right 4-term) — reassociation
//   flips the ok-mask at the boundary and fails validation (R2 lesson).
// ---------------------------------------------------------------------------

typedef float vf2 __attribute__((ext_vector_type(2)));

__global__ __launch_bounds__(BLOCK, 4) void resample_kernel(
    const float* __restrict__ vol,
    const float* __restrict__ T,
    float* __restrict__ out) {

    constexpr int TILES_PER_I = H_DIM / TILE_ROWS;            // 56
    constexpr int NBLK = D_DIM * TILES_PER_I;                 // 10752
    constexpr int PER_XCD = NBLK / NUM_XCD;                   // 1344

    const int b = blockIdx.x;
    const int xcd = b & (NUM_XCD - 1);
    const int q = b >> 3;
    const int sb = xcd * PER_XCD + q;          // slab-contiguous tile index
    const int i = sb / TILES_PER_I;
    const int jbase = (sb - i * TILES_PER_I) * TILE_ROWS;
    const int k = threadIdx.x;                 // 0..191

    const float t00 = T[0],  t01 = T[1],  t02 = T[2],  t03 = T[3];
    const float t10 = T[4],  t11 = T[5],  t12 = T[6],  t13 = T[7];
    const float t20 = T[8],  t21 = T[9],  t22 = T[10], t23 = T[11];

    const float fi = (float)i;
    const float fk = (float)k;

    vf2  p00[TILE_ROWS], p10[TILE_ROWS], p01[TILE_ROWS], p11[TILE_ROWS];
    float wi[TILE_ROWS], wj[TILE_ROWS], wk[TILE_ROWS];
    int   sel[TILE_ROWS];
    bool  okr[TILE_ROWS];

    // ---- Phase 1: addresses + ALL 16 float2 gathers issued ----
#pragma unroll
    for (int r = 0; r < TILE_ROWS; ++r) {
        const float fj = (float)(jbase + r);
        // EXACT R1 expression — do not reassociate (ok-mask boundary).
        const float di = t00 * fi + t01 * fj + t02 * fk + t03;
        const float dj = t10 * fi + t11 * fj + t12 * fk + t13;
        const float dk = t20 * fi + t21 * fj + t22 * fk + t23;

        okr[r] = (di > 0.f) & (dj > 0.f) & (dk > 0.f) &
                 (di <= (float)(D_DIM - 1)) &
                 (dj <= (float)(H_DIM - 1)) &
                 (dk <= (float)(W_DIM - 1));

        float ffi = fminf(fmaxf(floorf(di), 0.f), (float)(D_DIM - 1));
        float ffj = fminf(fmaxf(floorf(dj), 0.f), (float)(H_DIM - 1));
        float ffk = fminf(fmaxf(floorf(dk), 0.f), (float)(W_DIM - 1));

        wi[r] = di - ffi; wj[r] = dj - ffj; wk[r] = dk - ffk;

        const int i0 = (int)ffi, j0 = (int)ffj, k0 = (int)ffk;
        const int i1 = min(i0 + 1, D_DIM - 1);
        const int j1 = min(j0 + 1, H_DIM - 1);
        const int koff = min(k0, W_DIM - 2);   // 8B load stays in-bounds
        sel[r] = k0 - koff;                    // 1 iff k0 == W-1

        const int base00 = (i0 * H_DIM + j0) * W_DIM + koff;
        const int base01 = (i0 * H_DIM + j1) * W_DIM + koff;
        const int base10 = (i1 * H_DIM + j0) * W_DIM + koff;
        const int base11 = (i1 * H_DIM + j1) * W_DIM + koff;

        p00[r] = *(const vf2*)(vol + base00);
        p10[r] = *(const vf2*)(vol + base10);
        p01[r] = *(const vf2*)(vol + base01);
        p11[r] = *(const vf2*)(vol + base11);
    }

    // Hard phase boundary: drains vmcnt once for the whole batch and keeps
    // all 16 load results live in VGPRs (the compiler cannot interleave).
    __syncthreads();

    // ---- Phase 2: interpolate + coalesced nontemporal store ----
#pragma unroll
    for (int r = 0; r < TILE_ROWS; ++r) {
        const float c000 = sel[r] ? p00[r].y : p00[r].x;
        const float c100 = sel[r] ? p10[r].y : p10[r].x;
        const float c010 = sel[r] ? p01[r].y : p01[r].x;
        const float c110 = sel[r] ? p11[r].y : p11[r].x;
        const float c001 = p00[r].y;
        const float c101 = p10[r].y;
        const float c011 = p01[r].y;
        const float c111 = p11[r].y;

        const float omwi = 1.f - wi[r], omwj = 1.f - wj[r], omwk = 1.f - wk[r];
        const float val = ((c000 * omwi + c100 * wi[r]) * omwj +
                           (c010 * omwi + c110 * wi[r]) * wj[r]) * omwk +
                          ((c001 * omwi + c101 * wi[r]) * omwj +
                           (c011 * omwi + c111 * wi[r]) * wj[r]) * wk[r];
        const float res = okr[r] ? val : 0.f;
        __builtin_nontemporal_store(res, &out[(i * H_DIM + (jbase + r)) * W_DIM + k]);
    }
}

// ---------------------------------------------------------------------------

extern "C" void kernel_launch(void* const* d_in, const int* in_sizes, int n_in,
                              void* d_out, int out_size, void* d_ws, size_t ws_size,
                              hipStream_t stream) {
    const float* image_targ  = (const float*)d_in[0];
    const float* angle       = (const float*)d_in[1];
    const float* translation = (const float*)d_in[2];
    const float* scaling     = (const float*)d_in[3];
    const float* ref_v2r     = (const float*)d_in[4];
    const float* flo_v2r     = (const float*)d_in[5];
    float* out = (float*)d_out;
    float* Tmat = (float*)d_ws;  // 12 floats

    compute_T_kernel<<<1, 1, 0, stream>>>(angle, translation, scaling,
                                          ref_v2r, flo_v2r, Tmat);

    const int nblk = D_DIM * (H_DIM / TILE_ROWS);  // 10752
    resample_kernel<<<nblk, BLOCK, 0, stream>>>(image_targ, Tmat, out);
}